// Round 5
// baseline (218.506 us; speedup 1.0000x reference)
//
#include <hip/hip_runtime.h>
#include <hip/hip_bf16.h>
#include <type_traits>

typedef __hip_bfloat16 bf16;
typedef __attribute__((ext_vector_type(8))) short bf16x8;
typedef __attribute__((ext_vector_type(4))) float f32x4;

#define N_LOC 4096

__device__ __forceinline__ bf16 to_bf16(float f) { return __float2bfloat16(f); }

// async global->LDS DMA, 16B per lane; LDS dest = wave-uniform base + lane*16
__device__ __forceinline__ void dma16(const bf16* g, bf16* l) {
  __builtin_amdgcn_global_load_lds((const __attribute__((address_space(1))) unsigned int*)g,
                                   (__attribute__((address_space(3))) unsigned int*)l, 16, 0, 0);
}

// ---------------- prep: fused {f32->bf16 convert of Q,K,V,Wo} + {W transpose-pack} ----------------
__global__ __launch_bounds__(256) void prep(const float* __restrict__ Q, const float* __restrict__ K,
                                            const float* __restrict__ V, const float* __restrict__ Wo,
                                            bf16* __restrict__ Qb, bf16* __restrict__ Kb,
                                            bf16* __restrict__ Vb, bf16* __restrict__ Wob,
                                            const float* __restrict__ Wq, const float* __restrict__ Wk,
                                            const float* __restrict__ Wv,
                                            bf16* __restrict__ oq, bf16* __restrict__ ok,
                                            bf16* __restrict__ ov) {
  __shared__ float tile[64][65];
  if (blockIdx.x < 3328) {
    long i = ((long)blockIdx.x * 256 + threadIdx.x) * 8;
    const float* src;
    bf16* dst;
    long off;
    if (i < 2097152)      { src = Q;  dst = Qb;  off = i; }
    else if (i < 4194304) { src = K;  dst = Kb;  off = i - 2097152; }
    else if (i < 6291456) { src = V;  dst = Vb;  off = i - 4194304; }
    else                  { src = Wo; dst = Wob; off = i - 6291456; }
    float4 a = *(const float4*)&src[off];
    float4 b = *(const float4*)&src[off + 4];
    union { bf16 h[8]; bf16x8 v; } u;
    u.h[0] = to_bf16(a.x); u.h[1] = to_bf16(a.y); u.h[2] = to_bf16(a.z); u.h[3] = to_bf16(a.w);
    u.h[4] = to_bf16(b.x); u.h[5] = to_bf16(b.y); u.h[6] = to_bf16(b.z); u.h[7] = to_bf16(b.w);
    *(bf16x8*)&dst[off] = u.v;
  } else {
    int pid = blockIdx.x - 3328;            // 0..383  (old dims: x 8, y 16, z 3)
    int z = pid >> 7;
    int rem = pid & 127;
    int xx = rem & 7, y = rem >> 3;
    const float* W = (z == 0) ? Wq : (z == 1) ? Wk : Wv;
    bf16* out = (z == 0) ? oq : (z == 1) ? ok : ov;
    int DH = (z == 2) ? 256 : 128;
    int nt = DH >> 6;
    if (y >= 4 * nt) return;
    int h = y / nt, tt = y - h * nt;
    int d0 = xx * 64, t0 = tt * 64;
    for (int i = threadIdx.x; i < 4096; i += 256) {
      int r = i >> 6, c = i & 63;
      tile[r][c] = W[((size_t)h * 512 + d0 + r) * DH + t0 + c];
    }
    __syncthreads();
    for (int i = threadIdx.x; i < 4096; i += 256) {
      int t = i >> 6, d = i & 63;
      out[((size_t)(h * DH + t0 + t)) * 512 + d0 + d] = to_bf16(tile[d][t]);
    }
  }
}

// ---------------- 128xBN GEMM body, double-buffered counted-vmcnt staging ----------------
// MODE 0: C bf16 [M][N]; MODE 1: C f32 [M][N]; MODE 2: C bf16 TRANSPOSED (vT[col][row], ld 4096)
template <int BN, int MODE, typename OutT>
__device__ __forceinline__ void gemm_body(const bf16* __restrict__ A, const bf16* __restrict__ Bt,
                                          OutT* __restrict__ C, int N, int K, int m0, int n0,
                                          bf16* sm) {
  constexpr int WN = BN / 2, JN = WN / 16, NB = BN / 32;
  int tid = threadIdx.x, lane = tid & 63, w = tid >> 6;
  int quad = lane >> 4, l16 = lane & 15;
  int wm = (w >> 1) * 64, wn = (w & 1) * WN;
  int srow = lane >> 3;            // row-within-8-group staged by this lane
  int sG = (lane & 7) ^ srow;      // source granule for stored position lane&7

  bf16* Asb[2] = { sm, sm + 8192 };
  bf16* Bsb[2] = { sm + 16384, sm + 16384 + BN * 64 };

  const bf16* ga[4];
  const bf16* gb[NB];
#pragma unroll
  for (int j = 0; j < 4; j++) ga[j] = A + (long)(m0 + (4 * j + w) * 8 + srow) * K + sG * 8;
#pragma unroll
  for (int j = 0; j < NB; j++) gb[j] = Bt + (long)(n0 + (4 * j + w) * 8 + srow) * K + sG * 8;

  auto stage = [&](int b) {
#pragma unroll
    for (int j = 0; j < 4; j++) { dma16(ga[j], &Asb[b][(4 * j + w) * 512]); ga[j] += 64; }
#pragma unroll
    for (int j = 0; j < NB; j++) { dma16(gb[j], &Bsb[b][(4 * j + w) * 512]); gb[j] += 64; }
  };

  f32x4 acc[4][JN] = {};
  stage(0);
  asm volatile("" ::: "memory");
  int cur = 0;
  const int NK = K >> 6;
  for (int s = 0; s < NK; ++s) {
    if (s + 1 < NK) {
      stage(cur ^ 1);
      if constexpr (NB == 4) asm volatile("s_waitcnt vmcnt(8)" ::: "memory");
      else                   asm volatile("s_waitcnt vmcnt(6)" ::: "memory");
    } else {
      asm volatile("s_waitcnt vmcnt(0)" ::: "memory");
    }
    __builtin_amdgcn_s_barrier();      // tile s landed for all waves
    asm volatile("" ::: "memory");
    const bf16* Ac = Asb[cur];
    const bf16* Bc = Bsb[cur];
#pragma unroll
    for (int kk = 0; kk < 2; kk++) {
      bf16x8 af[4], bfr[JN];
#pragma unroll
      for (int i = 0; i < 4; i++) {
        int r = wm + i * 16 + l16;
        af[i] = *(const bf16x8*)&Ac[r * 64 + (((kk * 4 + quad) ^ r) & 7) * 8];
      }
#pragma unroll
      for (int j = 0; j < JN; j++) {
        int r = wn + j * 16 + l16;
        bfr[j] = *(const bf16x8*)&Bc[r * 64 + (((kk * 4 + quad) ^ r) & 7) * 8];
      }
#pragma unroll
      for (int i = 0; i < 4; i++)
#pragma unroll
        for (int j = 0; j < JN; j++)
          acc[i][j] = __builtin_amdgcn_mfma_f32_16x16x32_bf16(af[i], bfr[j], acc[i][j], 0, 0, 0);
    }
    asm volatile("" ::: "memory");
    __builtin_amdgcn_s_barrier();      // buf cur free for next stage's overwrite
    asm volatile("" ::: "memory");
    cur ^= 1;
  }

  if constexpr (MODE == 2) {
    bf16* tp = sm;  // [128][136] bf16 = 34.8 KB (sm is 64 KB)
#pragma unroll
    for (int i = 0; i < 4; i++)
#pragma unroll
      for (int j = 0; j < JN; j++)
#pragma unroll
        for (int r = 0; r < 4; r++)
          tp[(wn + j * 16 + l16) * 136 + wm + i * 16 + quad * 4 + r] = to_bf16(acc[i][j][r]);
    __syncthreads();
#pragma unroll
    for (int it = 0; it < 8; ++it) {
      int idx = it * 256 + tid;
      int rown = idx >> 4, c8 = (idx & 15) * 8;
      *(bf16x8*)&C[(size_t)(n0 + rown) * 4096 + m0 + c8] = *(const bf16x8*)&tp[rown * 136 + c8];
    }
  } else {
#pragma unroll
    for (int i = 0; i < 4; i++)
#pragma unroll
      for (int j = 0; j < JN; j++)
#pragma unroll
        for (int r = 0; r < 4; r++) {
          long row = m0 + wm + i * 16 + quad * 4 + r;
          long col = n0 + wn + j * 16 + l16;
          if constexpr (MODE == 0)
            C[row * N + col] = to_bf16(acc[i][j][r]);
          else
            C[row * N + col] = acc[i][j][r];
        }
  }
}

// merged q/k/v projections, exact 512-block grid; z==2 writes vT directly (transposed epilogue)
__global__ __launch_bounds__(256) void proj_gemm(const bf16* __restrict__ QKVb,
                                                 const bf16* __restrict__ Wt,
                                                 bf16* __restrict__ qkout,
                                                 bf16* __restrict__ vTout) {
  __shared__ __align__(16) bf16 sm[4 * 128 * 64];   // 64 KB
  int bid = blockIdx.x;
  if (bid < 256) {
    int z = bid >> 7;                 // 0:q 1:k
    int t = bid & 127;
    int m0 = (t & 31) * 128, n0 = (t >> 5) * 128;
    gemm_body<128, 0, bf16>(QKVb + (size_t)z * 2097152, Wt + (size_t)z * 262144,
                            qkout + (size_t)z * 2097152, 512, 512, m0, n0, sm);
  } else {
    int t = bid - 256;                // 0..255 -> v projection, 4096x1024
    int m0 = (t & 31) * 128, n0 = (t >> 5) * 128;
    gemm_body<128, 2, bf16>(QKVb + (size_t)2 * 2097152, Wt + (size_t)2 * 262144,
                            vTout, 1024, 512, m0, n0, sm);
  }
}

// output projection: 128x64 tiles -> 256 blocks
__global__ __launch_bounds__(256) void out_gemm(const bf16* __restrict__ xin,
                                                const bf16* __restrict__ Wob,
                                                float* __restrict__ outp) {
  __shared__ __align__(16) bf16 sm[2 * 128 * 64 + 2 * 64 * 64];   // 48 KB
  gemm_body<64, 1, float>(xin, Wob, outp, 512, 1024, blockIdx.x * 128, blockIdx.y * 64, sm);
}

// ---------------- fused attention ----------------
// qb,kb: [N][512]; vT: [1024][N]; x: [N][1024]
// R4: 128 q-rows per block (2x amortization of staged K/V + 2.25x MFMA per barrier).
// Block = (head, dvh, q0): 128 q x 128 dv; grid 256 = 1 block/CU. 8 waves = (cd,g):
//   S : wave computes S[q rows g*64..+63][keys cd*16..+15]  (4 m-frags)
//   PV: wave computes O[q rows g*64..+63][dv cd*32..+31 of this half]
// Double-buffered kt/vt, 3-barrier counted-vmcnt pattern (R1-proven), XOR-swizzled
// DMA staging, pt LDS round-trip for the P transpose.
__global__ __launch_bounds__(512, 2) void attn(const bf16* __restrict__ qb,
                                               const bf16* __restrict__ kb,
                                               const bf16* __restrict__ vT,
                                               bf16* __restrict__ x) {
  __shared__ __align__(16) bf16 kt[2][64 * 128];   // [key][dk] swizzled, 2x16 KB
  __shared__ __align__(16) bf16 vt[2][128 * 64];   // [dv-half][key] swizzled, 2x16 KB
  __shared__ __align__(16) bf16 pt[128 * 72];      // [q][key], padded (18 KB)
  __shared__ float Lrow[128];

  const int bid = blockIdx.x;                      // 256 blocks
  const int xcd = bid & 7;
  const int head = xcd & 3;                        // one (head,dvh) pair per XCD
  const int dvh = xcd >> 2;                        // dv half 0..1
  const int q0 = (bid >> 3) * 128;                 // 0..3968
  const int tid = threadIdx.x;
  const int lane = tid & 63, w = tid >> 6;
  const int quad = lane >> 4, l16 = lane & 15;
  const int cd = w & 3;   // S: 16-key col tile; PV: 32-dv group
  const int g = w >> 2;   // q half (64 rows each)

  // all-ones B-fragment: B[n][k] = (n==0) -> D[q][0] = sum_k P[q][k]
  bf16x8 onesf;
  {
    union { bf16 h[8]; bf16x8 v; } u;
    bf16 one = to_bf16(1.0f), zero = to_bf16(0.0f);
#pragma unroll
    for (int j = 0; j < 8; j++) u.h[j] = (l16 == 0) ? one : zero;
    onesf = u.v;
  }

  // preload q fragments (A-layout: m=l16, k=quad*8+j); 4 row-groups x 4 k-chunks
  bf16x8 qf[4][4];
#pragma unroll
  for (int i = 0; i < 4; i++) {
    const bf16* qrow = &qb[(size_t)(q0 + g * 64 + i * 16 + l16) * 512 + head * 128];
#pragma unroll
    for (int kk = 0; kk < 4; kk++) qf[i][kk] = *(const bf16x8*)&qrow[kk * 32 + quad * 8];
  }

  f32x4 oacc[4][2] = {};
  f32x4 oL[4] = {};
  const float scale = 1.0f / 64.0f;  // 1/sqrt(4096)

  // DMA source pointers (advance per tile). kt: 16 j-groups (4 key-rows x 128 dk);
  // vt: 16 j-groups (8 dv-rows x 64 keys). j = 2w+t2 (2 groups per wave each).
  const int j0 = 2 * w, j1 = 2 * w + 1;
  const bf16 *kp0, *kp1, *vp0, *vp1;
  {
    int r0 = 4 * j0 + (lane >> 4), r1 = 4 * j1 + (lane >> 4);
    int p = lane & 15;
    int G0 = (p & 8) | ((p ^ r0) & 7), G1 = (p & 8) | ((p ^ r1) & 7);
    kp0 = kb + (size_t)r0 * 512 + head * 128 + G0 * 8;
    kp1 = kb + (size_t)r1 * 512 + head * 128 + G1 * 8;
  }
  {
    int r0 = 8 * j0 + (lane >> 3), r1 = 8 * j1 + (lane >> 3);
    int p = lane & 7;
    int G0 = (p ^ r0) & 7, G1 = (p ^ r1) & 7;
    vp0 = vT + (size_t)(head * 256 + dvh * 128 + r0) * 4096 + G0 * 8;
    vp1 = vT + (size_t)(head * 256 + dvh * 128 + r1) * 4096 + G1 * 8;
  }

#define STAGE(b)                                        \
  do {                                                  \
    dma16(kp0, &kt[b][j0 * 512]);                       \
    dma16(kp1, &kt[b][j1 * 512]);                       \
    dma16(vp0, &vt[b][j0 * 512]);                       \
    dma16(vp1, &vt[b][j1 * 512]);                       \
    kp0 += 64 * 512; kp1 += 64 * 512;                   \
    vp0 += 64; vp1 += 64;                               \
  } while (0)

  STAGE(0);
  asm volatile("" ::: "memory");
  int cur = 0;

  for (int t = 0; t < 64; ++t) {
    // issue tile t+1's DMA into the other buffer, counted-wait for tile t
    if (t < 63) {
      STAGE(cur ^ 1);
      asm volatile("s_waitcnt vmcnt(4)" ::: "memory");
    } else {
      asm volatile("s_waitcnt vmcnt(0)" ::: "memory");
    }
    __builtin_amdgcn_s_barrier();          // A: tile t landed for all waves
    asm volatile("" ::: "memory");

    // ---- S = q @ k^T : q rows g*64..+63 (i=0..3), key cols cd*16..+15 ----
    const bf16* ktc = kt[cur];
    f32x4 sacc[4] = {};
#pragma unroll
    for (int kk = 0; kk < 4; kk++) {
      int R = cd * 16 + l16;
      int G = kk * 4 + quad;
      bf16x8 kf = *(const bf16x8*)&ktc[R * 128 + (((G ^ R) & 7) | (G & 8)) * 8];
#pragma unroll
      for (int i = 0; i < 4; i++)
        sacc[i] = __builtin_amdgcn_mfma_f32_16x16x32_bf16(qf[i][kk], kf, sacc[i], 0, 0, 0);
    }
#pragma unroll
    for (int i = 0; i < 4; i++)
#pragma unroll
      for (int r = 0; r < 4; r++)
        pt[(g * 64 + i * 16 + quad * 4 + r) * 72 + cd * 16 + l16] =
            to_bf16(__expf(sacc[i][r] * scale));
    asm volatile("s_waitcnt lgkmcnt(0)" ::: "memory");   // own pt writes visible
    __builtin_amdgcn_s_barrier();          // B: pt ready
    asm volatile("" ::: "memory");

    // ---- O += P @ v : q rows g*64..+63, dv cols cd*32..+31 (of this half) ----
    const bf16* vtc = vt[cur];
#pragma unroll
    for (int kk = 0; kk < 2; kk++) {
      bf16x8 pf[4];
#pragma unroll
      for (int i = 0; i < 4; i++)
        pf[i] = *(const bf16x8*)&pt[(g * 64 + i * 16 + l16) * 72 + kk * 32 + quad * 8];
#pragma unroll
      for (int c = 0; c < 2; c++) {
        int R = cd * 32 + c * 16 + l16;
        int G = kk * 4 + quad;
        bf16x8 vf = *(const bf16x8*)&vtc[R * 64 + ((G ^ R) & 7) * 8];
#pragma unroll
        for (int i = 0; i < 4; i++)
          oacc[i][c] = __builtin_amdgcn_mfma_f32_16x16x32_bf16(pf[i], vf, oacc[i][c], 0, 0, 0);
      }
      if (cd == 3) {  // wave-uniform: L column (full P tile available in pt)
#pragma unroll
        for (int i = 0; i < 4; i++)
          oL[i] = __builtin_amdgcn_mfma_f32_16x16x32_bf16(pf[i], onesf, oL[i], 0, 0, 0);
      }
    }
    asm volatile("" ::: "memory");
    __builtin_amdgcn_s_barrier();          // C: all reads of buf cur done
    asm volatile("" ::: "memory");
    cur ^= 1;
  }
#undef STAGE

  // L at lanes l16==0 of cd==3 waves (C-layout col 0)
  if (cd == 3 && l16 == 0) {
#pragma unroll
    for (int i = 0; i < 4; i++)
#pragma unroll
      for (int r = 0; r < 4; r++) Lrow[g * 64 + i * 16 + quad * 4 + r] = oL[i][r];
  }
  __syncthreads();

  // normalize + write x[n][head*256 + dvh*128 + dv]
#pragma unroll
  for (int i = 0; i < 4; i++)
#pragma unroll
    for (int c = 0; c < 2; c++)
#pragma unroll
      for (int r = 0; r < 4; r++) {
        int row = g * 64 + i * 16 + quad * 4 + r;
        float v = oacc[i][c][r] / Lrow[row];
        x[(size_t)(q0 + row) * 1024 + head * 256 + dvh * 128 + cd * 32 + c * 16 + l16] =
            to_bf16(v);
      }
}

// ---------------- launch ----------------
extern "C" void kernel_launch(void* const* d_in, const int* in_sizes, int n_in,
                              void* d_out, int out_size, void* d_ws, size_t ws_size,
                              hipStream_t stream) {
  const float* Q  = (const float*)d_in[0];
  const float* Km = (const float*)d_in[1];
  const float* V  = (const float*)d_in[2];
  const float* Wq = (const float*)d_in[3];
  const float* Wk = (const float*)d_in[4];
  const float* Wv = (const float*)d_in[5];
  const float* Wo = (const float*)d_in[6];
  float* out = (float*)d_out;

  bf16* ws  = (bf16*)d_ws;
  bf16* Qb  = ws;                 // 4096x512   (Qb,Kb,Vb contiguous)
  bf16* Kb  = Qb + 2097152;
  bf16* Vb  = Kb + 2097152;
  bf16* Wqt = Vb + 2097152;       // 512x512  (Wqt,Wkt,Wvt contiguous)
  bf16* Wkt = Wqt + 262144;
  bf16* Wvt = Wkt + 262144;       // 1024x512 (Bt)
  bf16* Wob = Wvt + 524288;       // 512x1024 (Bt = Wo as-is)
  bf16* qb  = Wob + 524288;       // 4096x512   (qb,kb contiguous)
  bf16* kb  = qb + 2097152;
  bf16* vT  = kb + 2097152;       // 1024x4096  (written directly by proj z==2)
  bf16* x   = vT + 4194304;       // 4096x1024

  prep<<<3712, 256, 0, stream>>>(Q, Km, V, Wo, Qb, Kb, Vb, Wob, Wq, Wk, Wv, Wqt, Wkt, Wvt);

  proj_gemm<<<512, 256, 0, stream>>>(Qb, Wqt, qb, vT);

  attn<<<256, 512, 0, stream>>>(qb, kb, vT, x);

  out_gemm<<<dim3(32, 8), 256, 0, stream>>>(x, Wob, out);
}